// Round 2
// baseline (2337.647 us; speedup 1.0000x reference)
//
#include <hip/hip_runtime.h>
#include <hip/hip_bf16.h>
#include <stdint.h>

#define N_NODES 100000
#define N_EDGES 1600000
#define D_FEAT 32
#define CUT_K 320000        // int(N_EDGES * 0.2)
#define COSKEY_NB 4096      // coskey grid: enough blocks for full occupancy
#define HC_NB 1000          // histc blocks; E = HC_NB * HC_SLICE exactly
#define HC_SLICE 1600
#define SCAN_NB ((N_NODES + 255) / 256)   // 391

struct SelState { unsigned long long prefix; unsigned int k; };

__global__ void deg_kernel(const int* __restrict__ dst, int* __restrict__ deg, int E) {
    int e = blockIdx.x * blockDim.x + threadIdx.x;
    if (e < E) atomicAdd(&deg[dst[e]], 1);
}

__global__ void norm_kernel(const int* __restrict__ deg, float* __restrict__ nrm, int N) {
    int i = blockIdx.x * blockDim.x + threadIdx.x;
    if (i < N) nrm[i] = 1.0f / sqrtf(fmaxf((float)deg[i], 1.0f));
}

// ---- parallel exclusive scan of deg (3 kernels) ----
__global__ void blocksum_kernel(const int* __restrict__ deg, int* __restrict__ bsum, int N) {
    int i = blockIdx.x * 256 + threadIdx.x;
    int v = (i < N) ? deg[i] : 0;
#pragma unroll
    for (int off = 32; off > 0; off >>= 1) v += __shfl_down(v, off, 64);
    __shared__ int ws4[4];
    if ((threadIdx.x & 63) == 0) ws4[threadIdx.x >> 6] = v;
    __syncthreads();
    if (threadIdx.x == 0) bsum[blockIdx.x] = ws4[0] + ws4[1] + ws4[2] + ws4[3];
}

__global__ void scanpartial_kernel(const int* __restrict__ bsum, int* __restrict__ boff, int B) {
    __shared__ int buf[512];
    int t = threadIdx.x;
    int v = (t < B) ? bsum[t] : 0;
    buf[t] = v;
    __syncthreads();
    for (int off = 1; off < 512; off <<= 1) {
        int u = (t >= off) ? buf[t - off] : 0;
        __syncthreads();
        buf[t] += u;
        __syncthreads();
    }
    if (t < B) boff[t] = buf[t] - v;   // exclusive
}

__global__ void writeoffs_kernel(const int* __restrict__ deg, const int* __restrict__ boff,
                                 int* __restrict__ offs, int* __restrict__ cursor, int N) {
    __shared__ int buf[256];
    int t = threadIdx.x;
    int i = blockIdx.x * 256 + t;
    int v = (i < N) ? deg[i] : 0;
    buf[t] = v;
    __syncthreads();
    for (int off = 1; off < 256; off <<= 1) {
        int u = (t >= off) ? buf[t - off] : 0;
        __syncthreads();
        buf[t] += u;
        __syncthreads();
    }
    int ex = buf[t] - v + boff[blockIdx.x];
    if (i < N) { offs[i] = ex; cursor[i] = ex; }
    if (i == N - 1) offs[N] = ex + v;   // == E
}

// scatter edges into CSR-by-dst slots; ONE packed 16B record per edge:
// csr[pos] = {src, dst, eid, 0}. One scattered store -> one dirtied line/edge
// (round-0's 3 separate 4B stores dirtied ~3 lines/edge -> 203MB writeback).
// 4 edges per thread for more outstanding scattered stores (MLP).
__global__ void fill_kernel(const int* __restrict__ src, const int* __restrict__ dst,
                            int* __restrict__ cursor,
                            uint4* __restrict__ csr, int E) {
    int e0 = blockIdx.x * 1024 + threadIdx.x;
#pragma unroll
    for (int u = 0; u < 4; ++u) {
        int e = e0 + u * 256;
        if (e < E) {
            int d = dst[e];
            int pos = atomicAdd(&cursor[d], 1);
            csr[pos] = make_uint4((unsigned int)src[e], (unsigned int)d,
                                  (unsigned int)e, 0u);
        }
    }
}

// nh = h / max(||h||,1e-12)  AND  hs = h * nrm  (fused); thread 0 also resets st
__global__ void rownorm_kernel(const float* __restrict__ h, float* __restrict__ nh,
                               float* __restrict__ hs, const float* __restrict__ nrm,
                               SelState* __restrict__ st, int N) {
    int i = blockIdx.x * blockDim.x + threadIdx.x;
    if (i == 0) { st->prefix = 0ull; st->k = CUT_K; }
    if (i >= N) return;
    const float4* hp = (const float4*)(h + (size_t)i * D_FEAT);
    float4 v[8];
    float ss = 0.f;
#pragma unroll
    for (int q = 0; q < 8; ++q) {
        v[q] = hp[q];
        ss += v[q].x * v[q].x + v[q].y * v[q].y + v[q].z * v[q].z + v[q].w * v[q].w;
    }
    float inv = 1.0f / fmaxf(sqrtf(ss), 1e-12f);
    float sc = nrm[i];
    float4* op = (float4*)(nh + (size_t)i * D_FEAT);
    float4* sp = (float4*)(hs + (size_t)i * D_FEAT);
#pragma unroll
    for (int q = 0; q < 8; ++q) {
        float4 ov = v[q];
        float4 sv = v[q];
        ov.x *= inv; ov.y *= inv; ov.z *= inv; ov.w *= inv;
        sv.x *= sc;  sv.y *= sc;  sv.z *= sc;  sv.w *= sc;
        op[q] = ov;
        sp[q] = sv;
    }
}

// last-block-folded 256-bin scan/select (replaces the separate scan8 launches).
// Reads ghist via device-scope atomics (cross-XCD coherent), extends prefix/k,
// zeroes ghist for the next pass, resets the ticket counter.
__device__ __forceinline__ void block_select(unsigned int* ghist, SelState* st,
                                             unsigned int* done) {
    __shared__ unsigned int buf[256];
    int t = threadIdx.x;
    unsigned int k = st->k;            // read before any write
    unsigned int s = atomicAdd(&ghist[t], 0u);   // coherent read
    buf[t] = s;
    __syncthreads();
    for (int off = 1; off < 256; off <<= 1) {
        unsigned int v = (t >= off) ? buf[t - off] : 0u;
        __syncthreads();
        buf[t] += v;
        __syncthreads();
    }
    unsigned int incl = buf[t];
    unsigned int excl = incl - s;
    if (excl < k && k <= incl) {       // exactly one thread wins
        st->prefix = (st->prefix << 8) | (unsigned long long)t;
        st->k = k - excl;
    }
    ghist[t] = 0u;                     // ready for next pass/hop
    if (t == 0) *done = 0u;            // reset ticket for next kernel
}

// edge-parallel cos keys (grid-stride, full occupancy + MLP). CSR order makes
// consecutive p share the same dst row -> b-gathers are L1/L2 hits; a-gather is
// the real traffic. Fused pass-0 histogram + last-block digit-0 select.
__global__ void coskey_kernel(const float* __restrict__ nh, const uint4* __restrict__ csr,
                              unsigned long long* __restrict__ keys,
                              unsigned int* __restrict__ ghist,
                              SelState* __restrict__ st,
                              unsigned int* __restrict__ done, int E) {
    __shared__ unsigned int lh[4][256];
    __shared__ unsigned int isLast;
    int t = threadIdx.x;
#pragma unroll
    for (int w = 0; w < 4; ++w) lh[w][t] = 0u;
    __syncthreads();
    int wave = t >> 6;
    int stride = gridDim.x * blockDim.x;
    for (int p = blockIdx.x * blockDim.x + t; p < E; p += stride) {
        uint4 r = csr[p];   // x=src, y=dst, z=eid
        const float4* a = (const float4*)(nh + (size_t)r.x * D_FEAT);
        const float4* b = (const float4*)(nh + (size_t)r.y * D_FEAT);
        float s = 0.f;
#pragma unroll
        for (int q = 0; q < 8; ++q) {
            float4 x = a[q], y = b[q];
            s += x.x * y.x + x.y * y.y + x.z * y.z + x.w * y.w;
        }
        unsigned int u = __float_as_uint(s);
        unsigned int so = (u & 0x80000000u) ? ~u : (u | 0x80000000u);
        unsigned long long key = ((unsigned long long)so << 32) | r.z;
        keys[p] = key;
        atomicAdd(&lh[wave][(unsigned int)(key >> 56)], 1u);
    }
    __syncthreads();
    unsigned int tot = lh[0][t] + lh[1][t] + lh[2][t] + lh[3][t];
    if (tot) atomicAdd(&ghist[t], tot);
    __threadfence();
    if (t == 0) isLast = (atomicAdd(done, 1u) == gridDim.x - 1) ? 1u : 0u;
    __syncthreads();
    if (isLast) block_select(ghist, st, done);
}

// compacting radix pass p (1..7), slice-deterministic, NO global atomics except
// the 256-bin ghist merge. Block b: input slice b (dense keys for pass 1),
// survivors appended to its private output slice via an LDS cursor.
// Last block performs the 256-bin select (no separate scan8 launch).
__global__ void histc_kernel(const unsigned long long* __restrict__ in,
                             const int* __restrict__ cnt_in,      // null => dense (pass 1)
                             unsigned long long* __restrict__ out,
                             int* __restrict__ cnt_out,
                             SelState* __restrict__ st,
                             unsigned int* __restrict__ ghist,
                             unsigned int* __restrict__ done, int pass) {
    __shared__ unsigned int lh[4][256];
    __shared__ unsigned int lcnt;
    __shared__ unsigned int isLast;
    int t = threadIdx.x, b = blockIdx.x;
#pragma unroll
    for (int w = 0; w < 4; ++w) lh[w][t] = 0u;
    if (t == 0) lcnt = 0u;
    __syncthreads();
    unsigned long long prefix = st->prefix;
    int n = cnt_in ? cnt_in[b] : HC_SLICE;
    const unsigned long long* sin = in + (size_t)b * HC_SLICE;
    unsigned long long* sout = out + (size_t)b * HC_SLICE;
    int wave = t >> 6;
    int fshift = 64 - 8 * pass;
    int dshift = 56 - 8 * pass;
    for (int i = t; i < n; i += 256) {
        unsigned long long key = sin[i];
        if ((key >> fshift) == prefix) {
            atomicAdd(&lh[wave][(unsigned int)((key >> dshift) & 0xFFull)], 1u);
            unsigned int slot = atomicAdd(&lcnt, 1u);   // LDS atomic, block-local
            sout[slot] = key;
        }
    }
    __syncthreads();
    if (t == 0) cnt_out[b] = (int)lcnt;
    unsigned int tot = lh[0][t] + lh[1][t] + lh[2][t] + lh[3][t];
    if (tot) atomicAdd(&ghist[t], tot);
    __threadfence();
    if (t == 0) isLast = (atomicAdd(done, 1u) == gridDim.x - 1) ? 1u : 0u;
    __syncthreads();
    if (isLast) block_select(ghist, st, done);
}

// pull aggregation: one 32-lane group per node walks its CSR segment.
// 8x unrolled with unconditional gathers for memory-level parallelism.
// src comes from the packed uint4 record (.x).
__global__ void aggregate_csr_kernel(const float* __restrict__ hs, float* __restrict__ h_out,
                                     const int* __restrict__ offs,
                                     const uint4* __restrict__ csr,
                                     const unsigned long long* __restrict__ keys,
                                     const SelState* __restrict__ st,
                                     const float* __restrict__ nrm, int N) {
    unsigned long long kth = st->prefix;   // cut_k-th smallest composite key
    int g = blockIdx.x * 8 + (threadIdx.x >> 5);
    int j = threadIdx.x & 31;
    if (g >= N) return;
    int lo = offs[g], hi = offs[g + 1];
    float acc = 0.f;
    int p = lo;
    for (; p + 8 <= hi; p += 8) {
        unsigned long long kk[8];
        unsigned int ss[8];
#pragma unroll
        for (int u = 0; u < 8; ++u) { kk[u] = keys[p + u]; ss[u] = csr[p + u].x; }
        float vv[8];
#pragma unroll
        for (int u = 0; u < 8; ++u) vv[u] = hs[(size_t)ss[u] * D_FEAT + j];
#pragma unroll
        for (int u = 0; u < 8; ++u) acc += (kk[u] > kth) ? vv[u] : 0.f;  // same seq FP order
    }
    for (; p < hi; ++p) {
        if (keys[p] > kth) acc += hs[(size_t)csr[p].x * D_FEAT + j];
    }
    h_out[(size_t)g * D_FEAT + j] = acc * nrm[g];
}

// out = h @ W^T ; stage W transposed in LDS (pad 33, conflict-free)
__global__ void fc_kernel(const float* __restrict__ h, const float* __restrict__ W,
                          float* __restrict__ out, int N) {
    __shared__ float Wt[32][33];
    int t = threadIdx.x;
    for (int i = t; i < 1024; i += 256) Wt[i & 31][i >> 5] = W[i];
    __syncthreads();
    int node = blockIdx.x * 8 + (t >> 5);
    if (node >= N) return;
    int o = t & 31;
    const float* hr = h + (size_t)node * D_FEAT;
    float acc = 0.f;
#pragma unroll
    for (int j = 0; j < 32; ++j) acc += hr[j] * Wt[j][o];
    out[(size_t)node * D_FEAT + o] = acc;
}

extern "C" void kernel_launch(void* const* d_in, const int* in_sizes, int n_in,
                              void* d_out, int out_size, void* d_ws, size_t ws_size,
                              hipStream_t stream) {
    const float* features = (const float*)d_in[0];
    const float* W        = (const float*)d_in[1];
    const int*   src      = (const int*)d_in[2];
    const int*   dst      = (const int*)d_in[3];
    float*       out      = (float*)d_out;

    char* ws = (char*)d_ws;
    size_t o = 0;
    auto take = [&](size_t bytes) -> char* {
        char* p = ws + o;
        o += (bytes + 255) & ~(size_t)255;
        return p;
    };
    int*                deg     = (int*)take((size_t)N_NODES * 4);
    float*              nrm     = (float*)take((size_t)N_NODES * 4);
    int*                offs    = (int*)take((size_t)(N_NODES + 1) * 4);
    int*                cursor  = (int*)take((size_t)N_NODES * 4);
    uint4*              csr     = (uint4*)take((size_t)N_EDGES * 16);
    float*              hA      = (float*)take((size_t)N_NODES * D_FEAT * 4);
    float*              hB      = (float*)take((size_t)N_NODES * D_FEAT * 4);
    float*              nh      = (float*)take((size_t)N_NODES * D_FEAT * 4);
    float*              hs      = (float*)take((size_t)N_NODES * D_FEAT * 4);
    unsigned long long* keys    = (unsigned long long*)take((size_t)N_EDGES * 8);
    unsigned int*       ghist   = (unsigned int*)take((size_t)256 * 4);
    SelState*           st      = (SelState*)take(256);
    unsigned int*       done    = (unsigned int*)take(256);
    int*                bsum    = (int*)take((size_t)SCAN_NB * 4);
    int*                boff    = (int*)take((size_t)SCAN_NB * 4);
    int*                cnt_a   = (int*)take((size_t)HC_NB * 4);
    int*                cnt_b   = (int*)take((size_t)HC_NB * 4);

    // candidate slice buffers alias dead memory during the radix passes:
    // nh is dead after coskey; hB is written only by hop-2 aggregate (after selection).
    unsigned long long* candA = (unsigned long long*)nh;
    unsigned long long* candB = (unsigned long long*)hB;

    hipMemsetAsync(deg, 0, (size_t)N_NODES * 4, stream);
    hipMemsetAsync(ghist, 0, (size_t)256 * 4, stream);
    hipMemsetAsync(done, 0, 4, stream);

    deg_kernel<<<(N_EDGES + 255) / 256, 256, 0, stream>>>(dst, deg, N_EDGES);
    norm_kernel<<<(N_NODES + 255) / 256, 256, 0, stream>>>(deg, nrm, N_NODES);
    blocksum_kernel<<<SCAN_NB, 256, 0, stream>>>(deg, bsum, N_NODES);
    scanpartial_kernel<<<1, 512, 0, stream>>>(bsum, boff, SCAN_NB);
    writeoffs_kernel<<<SCAN_NB, 256, 0, stream>>>(deg, boff, offs, cursor, N_NODES);
    fill_kernel<<<(N_EDGES + 1023) / 1024, 256, 0, stream>>>(src, dst, cursor,
                                                             csr, N_EDGES);

    const float* hin = features;
    float* houts[2] = { hA, hB };
    for (int hop = 0; hop < 2; ++hop) {
        float* hout = houts[hop];
        rownorm_kernel<<<(N_NODES + 255) / 256, 256, 0, stream>>>(hin, nh, hs, nrm, st, N_NODES);
        coskey_kernel<<<COSKEY_NB, 256, 0, stream>>>(nh, csr, keys, ghist, st, done, N_EDGES);
        for (int pass = 1; pass < 8; ++pass) {
            const unsigned long long* in =
                (pass == 1) ? keys : ((pass & 1) ? candB : candA);
            const int* cin = (pass == 1) ? (const int*)nullptr
                                         : ((pass & 1) ? cnt_b : cnt_a);
            unsigned long long* outc = (pass & 1) ? candA : candB;
            int* cout = (pass & 1) ? cnt_a : cnt_b;
            histc_kernel<<<HC_NB, 256, 0, stream>>>(in, cin, outc, cout, st, ghist, done, pass);
        }
        aggregate_csr_kernel<<<(N_NODES + 7) / 8, 256, 0, stream>>>(
            hs, hout, offs, csr, keys, st, nrm, N_NODES);
        hin = hout;
    }
    fc_kernel<<<(N_NODES + 7) / 8, 256, 0, stream>>>(hin, W, out, N_NODES);
}

// Round 3
// 672.278 us; speedup vs baseline: 3.4772x; 3.4772x over previous
//
#include <hip/hip_runtime.h>
#include <hip/hip_bf16.h>
#include <stdint.h>

#define N_NODES 100000
#define N_EDGES 1600000
#define D_FEAT 32
#define CUT_K 320000        // int(N_EDGES * 0.2)
#define COSKEY_NB 4096      // coskey grid: enough blocks for full occupancy
#define HC_NB 1000          // histc blocks; E = HC_NB * HC_SLICE exactly
#define HC_SLICE 1600
#define SCAN_NB ((N_NODES + 255) / 256)   // 391

struct SelState { unsigned long long prefix; unsigned int k; };

__global__ void deg_kernel(const int* __restrict__ dst, int* __restrict__ deg, int E) {
    int e = blockIdx.x * blockDim.x + threadIdx.x;
    if (e < E) atomicAdd(&deg[dst[e]], 1);
}

__global__ void norm_kernel(const int* __restrict__ deg, float* __restrict__ nrm, int N) {
    int i = blockIdx.x * blockDim.x + threadIdx.x;
    if (i < N) nrm[i] = 1.0f / sqrtf(fmaxf((float)deg[i], 1.0f));
}

// ---- parallel exclusive scan of deg (3 kernels) ----
__global__ void blocksum_kernel(const int* __restrict__ deg, int* __restrict__ bsum, int N) {
    int i = blockIdx.x * 256 + threadIdx.x;
    int v = (i < N) ? deg[i] : 0;
#pragma unroll
    for (int off = 32; off > 0; off >>= 1) v += __shfl_down(v, off, 64);
    __shared__ int ws4[4];
    if ((threadIdx.x & 63) == 0) ws4[threadIdx.x >> 6] = v;
    __syncthreads();
    if (threadIdx.x == 0) bsum[blockIdx.x] = ws4[0] + ws4[1] + ws4[2] + ws4[3];
}

__global__ void scanpartial_kernel(const int* __restrict__ bsum, int* __restrict__ boff, int B) {
    __shared__ int buf[512];
    int t = threadIdx.x;
    int v = (t < B) ? bsum[t] : 0;
    buf[t] = v;
    __syncthreads();
    for (int off = 1; off < 512; off <<= 1) {
        int u = (t >= off) ? buf[t - off] : 0;
        __syncthreads();
        buf[t] += u;
        __syncthreads();
    }
    if (t < B) boff[t] = buf[t] - v;   // exclusive
}

__global__ void writeoffs_kernel(const int* __restrict__ deg, const int* __restrict__ boff,
                                 int* __restrict__ offs, int* __restrict__ cursor, int N) {
    __shared__ int buf[256];
    int t = threadIdx.x;
    int i = blockIdx.x * 256 + t;
    int v = (i < N) ? deg[i] : 0;
    buf[t] = v;
    __syncthreads();
    for (int off = 1; off < 256; off <<= 1) {
        int u = (t >= off) ? buf[t - off] : 0;
        __syncthreads();
        buf[t] += u;
        __syncthreads();
    }
    int ex = buf[t] - v + boff[blockIdx.x];
    if (i < N) { offs[i] = ex; cursor[i] = ex; }
    if (i == N - 1) offs[N] = ex + v;   // == E
}

// scatter edges into CSR-by-dst slots; ONE packed 16B record per edge:
// csr[pos] = {src, dst, eid, 0} -> one dirtied line per edge (round-0's three
// 4B stores dirtied ~3 lines/edge -> 203MB writeback). 4 edges/thread for MLP.
__global__ void fill_kernel(const int* __restrict__ src, const int* __restrict__ dst,
                            int* __restrict__ cursor,
                            uint4* __restrict__ csr, int E) {
    int e0 = blockIdx.x * 1024 + threadIdx.x;
#pragma unroll
    for (int u = 0; u < 4; ++u) {
        int e = e0 + u * 256;
        if (e < E) {
            int d = dst[e];
            int pos = atomicAdd(&cursor[d], 1);
            csr[pos] = make_uint4((unsigned int)src[e], (unsigned int)d,
                                  (unsigned int)e, 0u);
        }
    }
}

// nh = h / max(||h||,1e-12)  AND  hs = h * nrm  (fused)
__global__ void rownorm_kernel(const float* __restrict__ h, float* __restrict__ nh,
                               float* __restrict__ hs, const float* __restrict__ nrm,
                               int N) {
    int i = blockIdx.x * blockDim.x + threadIdx.x;
    if (i >= N) return;
    const float4* hp = (const float4*)(h + (size_t)i * D_FEAT);
    float4 v[8];
    float ss = 0.f;
#pragma unroll
    for (int q = 0; q < 8; ++q) {
        v[q] = hp[q];
        ss += v[q].x * v[q].x + v[q].y * v[q].y + v[q].z * v[q].z + v[q].w * v[q].w;
    }
    float inv = 1.0f / fmaxf(sqrtf(ss), 1e-12f);
    float sc = nrm[i];
    float4* op = (float4*)(nh + (size_t)i * D_FEAT);
    float4* sp = (float4*)(hs + (size_t)i * D_FEAT);
#pragma unroll
    for (int q = 0; q < 8; ++q) {
        float4 ov = v[q];
        float4 sv = v[q];
        ov.x *= inv; ov.y *= inv; ov.z *= inv; ov.w *= inv;
        sv.x *= sc;  sv.y *= sc;  sv.z *= sc;  sv.w *= sc;
        op[q] = ov;
        sp[q] = sv;
    }
}

// Redundant per-block 256-bin scan/select. Every block of a kernel reads the
// PREVIOUS kernel's histogram (visible via stream kernel-boundary ordering —
// no fences needed) and deterministically derives the same (prefix, k).
// Must be called by ALL 256 threads. Returns new prefix; *k_out = new k.
__device__ __forceinline__ unsigned long long scan_select(
        const unsigned int* __restrict__ hist,
        unsigned long long pfx_in, unsigned int k_in,
        unsigned int* k_out) {
    __shared__ unsigned int sbuf[256];
    __shared__ unsigned long long s_pfx;
    __shared__ unsigned int s_k;
    int t = threadIdx.x;
    unsigned int s = hist[t];
    sbuf[t] = s;
    __syncthreads();
    for (int off = 1; off < 256; off <<= 1) {
        unsigned int v = (t >= off) ? sbuf[t - off] : 0u;
        __syncthreads();
        sbuf[t] += v;
        __syncthreads();
    }
    unsigned int incl = sbuf[t];
    unsigned int excl = incl - s;
    if (excl < k_in && k_in <= incl) {          // exactly one thread wins
        s_pfx = (pfx_in << 8) | (unsigned long long)t;
        s_k = k_in - excl;
    }
    __syncthreads();
    if (k_out) *k_out = s_k;
    return s_pfx;
}

// edge-parallel cos keys (grid-stride, full occupancy + MLP). CSR order makes
// consecutive p share the same dst row -> b-gathers are L1/L2 hits. Fused
// digit-0 histogram into hist0. No fences, no select here.
__global__ void coskey_kernel(const float* __restrict__ nh, const uint4* __restrict__ csr,
                              unsigned long long* __restrict__ keys,
                              unsigned int* __restrict__ hist0, int E) {
    __shared__ unsigned int lh[4][256];
    int t = threadIdx.x;
#pragma unroll
    for (int w = 0; w < 4; ++w) lh[w][t] = 0u;
    __syncthreads();
    int wave = t >> 6;
    int stride = gridDim.x * blockDim.x;
    for (int p = blockIdx.x * blockDim.x + t; p < E; p += stride) {
        uint4 r = csr[p];   // x=src, y=dst, z=eid
        const float4* a = (const float4*)(nh + (size_t)r.x * D_FEAT);
        const float4* b = (const float4*)(nh + (size_t)r.y * D_FEAT);
        float s = 0.f;
#pragma unroll
        for (int q = 0; q < 8; ++q) {
            float4 x = a[q], y = b[q];
            s += x.x * y.x + x.y * y.y + x.z * y.z + x.w * y.w;
        }
        unsigned int u = __float_as_uint(s);
        unsigned int so = (u & 0x80000000u) ? ~u : (u | 0x80000000u);
        unsigned long long key = ((unsigned long long)so << 32) | r.z;
        keys[p] = key;
        atomicAdd(&lh[wave][(unsigned int)(key >> 56)], 1u);
    }
    __syncthreads();
    unsigned int tot = lh[0][t] + lh[1][t] + lh[2][t] + lh[3][t];
    if (tot) atomicAdd(&hist0[t], tot);
}

// compacting radix pass p (1..7). Starts with a redundant scan of hist_prev
// (previous kernel's output) to derive this pass's (prefix,k); block 0 writes
// the derived state to st_out (read only by LATER kernels -> race-free).
// Then: filter survivors by prefix, histogram next digit into hist_cur,
// compact survivors into the block's private output slice.
__global__ void histc_kernel(const unsigned long long* __restrict__ in,
                             const int* __restrict__ cnt_in,      // null => dense (pass 1)
                             unsigned long long* __restrict__ out,
                             int* __restrict__ cnt_out,
                             const SelState* __restrict__ st_in,  // null => {0, CUT_K}
                             SelState* __restrict__ st_out,
                             const unsigned int* __restrict__ hist_prev,
                             unsigned int* __restrict__ hist_cur, int pass) {
    __shared__ unsigned int lh[4][256];
    __shared__ unsigned int lcnt;
    int t = threadIdx.x, b = blockIdx.x;
#pragma unroll
    for (int w = 0; w < 4; ++w) lh[w][t] = 0u;
    if (t == 0) lcnt = 0u;

    unsigned long long pfx_in = st_in ? st_in->prefix : 0ull;
    unsigned int k_in = st_in ? st_in->k : (unsigned int)CUT_K;
    unsigned int k_cur;
    unsigned long long prefix = scan_select(hist_prev, pfx_in, k_in, &k_cur);
    if (b == 0 && t == 0) { st_out->prefix = prefix; st_out->k = k_cur; }
    __syncthreads();

    int n = cnt_in ? cnt_in[b] : HC_SLICE;
    const unsigned long long* sin = in + (size_t)b * HC_SLICE;
    unsigned long long* sout = out + (size_t)b * HC_SLICE;
    int wave = t >> 6;
    int fshift = 64 - 8 * pass;
    int dshift = 56 - 8 * pass;
    for (int i = t; i < n; i += 256) {
        unsigned long long key = sin[i];
        if ((key >> fshift) == prefix) {
            atomicAdd(&lh[wave][(unsigned int)((key >> dshift) & 0xFFull)], 1u);
            unsigned int slot = atomicAdd(&lcnt, 1u);   // LDS atomic, block-local
            sout[slot] = key;
        }
    }
    __syncthreads();
    if (t == 0) cnt_out[b] = (int)lcnt;
    unsigned int tot = lh[0][t] + lh[1][t] + lh[2][t] + lh[3][t];
    if (tot) atomicAdd(&hist_cur[t], tot);
}

// pull aggregation: one 32-lane group per node walks its CSR segment.
// Starts with the redundant FINAL scan (hist7 + st7 -> full 64-bit kth key).
// 8x unrolled unconditional gathers for MLP; src from packed uint4 (.x).
__global__ void aggregate_csr_kernel(const float* __restrict__ hs, float* __restrict__ h_out,
                                     const int* __restrict__ offs,
                                     const uint4* __restrict__ csr,
                                     const unsigned long long* __restrict__ keys,
                                     const SelState* __restrict__ st7,
                                     const unsigned int* __restrict__ hist7,
                                     const float* __restrict__ nrm, int N) {
    unsigned long long kth = scan_select(hist7, st7->prefix, st7->k, nullptr);
    int g = blockIdx.x * 8 + (threadIdx.x >> 5);
    int j = threadIdx.x & 31;
    if (g >= N) return;
    int lo = offs[g], hi = offs[g + 1];
    float acc = 0.f;
    int p = lo;
    for (; p + 8 <= hi; p += 8) {
        unsigned long long kk[8];
        unsigned int ss[8];
#pragma unroll
        for (int u = 0; u < 8; ++u) { kk[u] = keys[p + u]; ss[u] = csr[p + u].x; }
        float vv[8];
#pragma unroll
        for (int u = 0; u < 8; ++u) vv[u] = hs[(size_t)ss[u] * D_FEAT + j];
#pragma unroll
        for (int u = 0; u < 8; ++u) acc += (kk[u] > kth) ? vv[u] : 0.f;  // same seq FP order
    }
    for (; p < hi; ++p) {
        if (keys[p] > kth) acc += hs[(size_t)csr[p].x * D_FEAT + j];
    }
    h_out[(size_t)g * D_FEAT + j] = acc * nrm[g];
}

// out = h @ W^T ; stage W transposed in LDS (pad 33, conflict-free)
__global__ void fc_kernel(const float* __restrict__ h, const float* __restrict__ W,
                          float* __restrict__ out, int N) {
    __shared__ float Wt[32][33];
    int t = threadIdx.x;
    for (int i = t; i < 1024; i += 256) Wt[i & 31][i >> 5] = W[i];
    __syncthreads();
    int node = blockIdx.x * 8 + (t >> 5);
    if (node >= N) return;
    int o = t & 31;
    const float* hr = h + (size_t)node * D_FEAT;
    float acc = 0.f;
#pragma unroll
    for (int j = 0; j < 32; ++j) acc += hr[j] * Wt[j][o];
    out[(size_t)node * D_FEAT + o] = acc;
}

extern "C" void kernel_launch(void* const* d_in, const int* in_sizes, int n_in,
                              void* d_out, int out_size, void* d_ws, size_t ws_size,
                              hipStream_t stream) {
    const float* features = (const float*)d_in[0];
    const float* W        = (const float*)d_in[1];
    const int*   src      = (const int*)d_in[2];
    const int*   dst      = (const int*)d_in[3];
    float*       out      = (float*)d_out;

    char* ws = (char*)d_ws;
    size_t o = 0;
    auto take = [&](size_t bytes) -> char* {
        char* p = ws + o;
        o += (bytes + 255) & ~(size_t)255;
        return p;
    };
    int*                deg     = (int*)take((size_t)N_NODES * 4);
    float*              nrm     = (float*)take((size_t)N_NODES * 4);
    int*                offs    = (int*)take((size_t)(N_NODES + 1) * 4);
    int*                cursor  = (int*)take((size_t)N_NODES * 4);
    uint4*              csr     = (uint4*)take((size_t)N_EDGES * 16);
    float*              hA      = (float*)take((size_t)N_NODES * D_FEAT * 4);
    float*              hB      = (float*)take((size_t)N_NODES * D_FEAT * 4);
    float*              nh      = (float*)take((size_t)N_NODES * D_FEAT * 4);
    float*              hs      = (float*)take((size_t)N_NODES * D_FEAT * 4);
    unsigned long long* keys    = (unsigned long long*)take((size_t)N_EDGES * 8);
    unsigned int*       hist    = (unsigned int*)take((size_t)16 * 256 * 4); // per-pass bins
    SelState*           stArr   = (SelState*)take((size_t)16 * sizeof(SelState));
    int*                bsum    = (int*)take((size_t)SCAN_NB * 4);
    int*                boff    = (int*)take((size_t)SCAN_NB * 4);
    int*                cnt_a   = (int*)take((size_t)HC_NB * 4);
    int*                cnt_b   = (int*)take((size_t)HC_NB * 4);

    // candidate slice buffers alias dead memory during the radix passes:
    // nh is dead after coskey; hB is written only by hop-2 aggregate (after selection).
    unsigned long long* candA = (unsigned long long*)nh;
    unsigned long long* candB = (unsigned long long*)hB;

    hipMemsetAsync(deg, 0, (size_t)N_NODES * 4, stream);
    hipMemsetAsync(hist, 0, (size_t)16 * 256 * 4, stream);

    deg_kernel<<<(N_EDGES + 255) / 256, 256, 0, stream>>>(dst, deg, N_EDGES);
    norm_kernel<<<(N_NODES + 255) / 256, 256, 0, stream>>>(deg, nrm, N_NODES);
    blocksum_kernel<<<SCAN_NB, 256, 0, stream>>>(deg, bsum, N_NODES);
    scanpartial_kernel<<<1, 512, 0, stream>>>(bsum, boff, SCAN_NB);
    writeoffs_kernel<<<SCAN_NB, 256, 0, stream>>>(deg, boff, offs, cursor, N_NODES);
    fill_kernel<<<(N_EDGES + 1023) / 1024, 256, 0, stream>>>(src, dst, cursor,
                                                             csr, N_EDGES);

    const float* hin = features;
    float* houts[2] = { hA, hB };
    for (int hop = 0; hop < 2; ++hop) {
        float* hout = houts[hop];
        unsigned int* hh = hist + (size_t)hop * 8 * 256;   // 8 per-pass histograms
        SelState*     hs_st = stArr + (size_t)hop * 8;     // slots [1..7] used
        rownorm_kernel<<<(N_NODES + 255) / 256, 256, 0, stream>>>(hin, nh, hs, nrm, N_NODES);
        coskey_kernel<<<COSKEY_NB, 256, 0, stream>>>(nh, csr, keys, hh, N_EDGES);
        for (int pass = 1; pass < 8; ++pass) {
            const unsigned long long* in =
                (pass == 1) ? keys : ((pass & 1) ? candB : candA);
            const int* cin = (pass == 1) ? (const int*)nullptr
                                         : ((pass & 1) ? cnt_b : cnt_a);
            unsigned long long* outc = (pass & 1) ? candA : candB;
            int* cout = (pass & 1) ? cnt_a : cnt_b;
            const SelState* sin_st = (pass == 1) ? (const SelState*)nullptr
                                                 : (hs_st + pass - 1);
            histc_kernel<<<HC_NB, 256, 0, stream>>>(in, cin, outc, cout,
                                                    sin_st, hs_st + pass,
                                                    hh + (pass - 1) * 256,
                                                    hh + pass * 256, pass);
        }
        aggregate_csr_kernel<<<(N_NODES + 7) / 8, 256, 0, stream>>>(
            hs, hout, offs, csr, keys, hs_st + 7, hh + 7 * 256, nrm, N_NODES);
        hin = hout;
    }
    fc_kernel<<<(N_NODES + 7) / 8, 256, 0, stream>>>(hin, W, out, N_NODES);
}

// Round 4
// 646.525 us; speedup vs baseline: 3.6157x; 1.0398x over previous
//
#include <hip/hip_runtime.h>
#include <hip/hip_bf16.h>
#include <stdint.h>

#define N_NODES 100000
#define N_EDGES 1600000
#define D_FEAT 32
#define CUT_K 320000        // int(N_EDGES * 0.2)
#define COSKEY_NB 4096      // coskey grid: enough blocks for full occupancy
#define HC_NB 1000          // histc blocks; E = HC_NB * HC_SLICE exactly
#define HC_SLICE 1600
#define SCAN_NB ((N_NODES + 255) / 256)   // 391
#define TAILCAP 400000      // tail scratch slots per ping-pong half

struct SelState { unsigned long long prefix; unsigned int k; };

__global__ void deg_kernel(const int* __restrict__ dst, int* __restrict__ deg, int E) {
    int e = blockIdx.x * blockDim.x + threadIdx.x;
    if (e < E) atomicAdd(&deg[dst[e]], 1);
}

__global__ void norm_kernel(const int* __restrict__ deg, float* __restrict__ nrm, int N) {
    int i = blockIdx.x * blockDim.x + threadIdx.x;
    if (i < N) nrm[i] = 1.0f / sqrtf(fmaxf((float)deg[i], 1.0f));
}

// ---- parallel exclusive scan of deg (3 kernels) ----
__global__ void blocksum_kernel(const int* __restrict__ deg, int* __restrict__ bsum, int N) {
    int i = blockIdx.x * 256 + threadIdx.x;
    int v = (i < N) ? deg[i] : 0;
#pragma unroll
    for (int off = 32; off > 0; off >>= 1) v += __shfl_down(v, off, 64);
    __shared__ int ws4[4];
    if ((threadIdx.x & 63) == 0) ws4[threadIdx.x >> 6] = v;
    __syncthreads();
    if (threadIdx.x == 0) bsum[blockIdx.x] = ws4[0] + ws4[1] + ws4[2] + ws4[3];
}

__global__ void scanpartial_kernel(const int* __restrict__ bsum, int* __restrict__ boff, int B) {
    __shared__ int buf[512];
    int t = threadIdx.x;
    int v = (t < B) ? bsum[t] : 0;
    buf[t] = v;
    __syncthreads();
    for (int off = 1; off < 512; off <<= 1) {
        int u = (t >= off) ? buf[t - off] : 0;
        __syncthreads();
        buf[t] += u;
        __syncthreads();
    }
    if (t < B) boff[t] = buf[t] - v;   // exclusive
}

__global__ void writeoffs_kernel(const int* __restrict__ deg, const int* __restrict__ boff,
                                 int* __restrict__ offs, int* __restrict__ cursor, int N) {
    __shared__ int buf[256];
    int t = threadIdx.x;
    int i = blockIdx.x * 256 + t;
    int v = (i < N) ? deg[i] : 0;
    buf[t] = v;
    __syncthreads();
    for (int off = 1; off < 256; off <<= 1) {
        int u = (t >= off) ? buf[t - off] : 0;
        __syncthreads();
        buf[t] += u;
        __syncthreads();
    }
    int ex = buf[t] - v + boff[blockIdx.x];
    if (i < N) { offs[i] = ex; cursor[i] = ex; }
    if (i == N - 1) offs[N] = ex + v;   // == E
}

// scatter edges into CSR-by-dst slots; ONE packed 16B record per edge
// (csr[pos] = {src, dst, eid, 0} -> one dirtied line/edge). 1 edge/thread:
// the scatter is LATENCY-bound (820 GB/s << peak), so max TLP wins (r3 lesson:
// 4 edges/thread cut threads 4x -> occupancy 54% and dur +25%).
__global__ void fill_kernel(const int* __restrict__ src, const int* __restrict__ dst,
                            int* __restrict__ cursor,
                            uint4* __restrict__ csr, int E) {
    int e = blockIdx.x * blockDim.x + threadIdx.x;
    if (e >= E) return;
    int d = dst[e];
    int pos = atomicAdd(&cursor[d], 1);
    csr[pos] = make_uint4((unsigned int)src[e], (unsigned int)d, (unsigned int)e, 0u);
}

// nh = h / max(||h||,1e-12)  AND  hs = h * nrm  (fused)
__global__ void rownorm_kernel(const float* __restrict__ h, float* __restrict__ nh,
                               float* __restrict__ hs, const float* __restrict__ nrm,
                               int N) {
    int i = blockIdx.x * blockDim.x + threadIdx.x;
    if (i >= N) return;
    const float4* hp = (const float4*)(h + (size_t)i * D_FEAT);
    float4 v[8];
    float ss = 0.f;
#pragma unroll
    for (int q = 0; q < 8; ++q) {
        v[q] = hp[q];
        ss += v[q].x * v[q].x + v[q].y * v[q].y + v[q].z * v[q].z + v[q].w * v[q].w;
    }
    float inv = 1.0f / fmaxf(sqrtf(ss), 1e-12f);
    float sc = nrm[i];
    float4* op = (float4*)(nh + (size_t)i * D_FEAT);
    float4* sp = (float4*)(hs + (size_t)i * D_FEAT);
#pragma unroll
    for (int q = 0; q < 8; ++q) {
        float4 ov = v[q];
        float4 sv = v[q];
        ov.x *= inv; ov.y *= inv; ov.z *= inv; ov.w *= inv;
        sv.x *= sc;  sv.y *= sc;  sv.z *= sc;  sv.w *= sc;
        op[q] = ov;
        sp[q] = sv;
    }
}

// Redundant per-block 256-bin scan/select. Every block of a kernel reads the
// PREVIOUS kernel's histogram (visible via stream kernel-boundary ordering —
// no fences needed) and deterministically derives the same (prefix, k).
// Must be called by ALL 256 threads. Returns new prefix; *k_out = new k.
__device__ __forceinline__ unsigned long long scan_select(
        const unsigned int* __restrict__ hist,
        unsigned long long pfx_in, unsigned int k_in,
        unsigned int* k_out) {
    __shared__ unsigned int sbuf[256];
    __shared__ unsigned long long s_pfx;
    __shared__ unsigned int s_k;
    int t = threadIdx.x;
    unsigned int s = hist[t];
    sbuf[t] = s;
    __syncthreads();
    for (int off = 1; off < 256; off <<= 1) {
        unsigned int v = (t >= off) ? sbuf[t - off] : 0u;
        __syncthreads();
        sbuf[t] += v;
        __syncthreads();
    }
    unsigned int incl = sbuf[t];
    unsigned int excl = incl - s;
    if (excl < k_in && k_in <= incl) {          // exactly one thread wins
        s_pfx = (pfx_in << 8) | (unsigned long long)t;
        s_k = k_in - excl;
    }
    __syncthreads();
    if (k_out) *k_out = s_k;
    return s_pfx;
}

// edge-parallel cos keys (grid-stride, full occupancy + MLP). CSR order makes
// consecutive p share the same dst row -> b-gathers are L1/L2 hits. Fused
// digit-0 histogram into hist0.
__global__ void coskey_kernel(const float* __restrict__ nh, const uint4* __restrict__ csr,
                              unsigned long long* __restrict__ keys,
                              unsigned int* __restrict__ hist0, int E) {
    __shared__ unsigned int lh[4][256];
    int t = threadIdx.x;
#pragma unroll
    for (int w = 0; w < 4; ++w) lh[w][t] = 0u;
    __syncthreads();
    int wave = t >> 6;
    int stride = gridDim.x * blockDim.x;
    for (int p = blockIdx.x * blockDim.x + t; p < E; p += stride) {
        uint4 r = csr[p];   // x=src, y=dst, z=eid
        const float4* a = (const float4*)(nh + (size_t)r.x * D_FEAT);
        const float4* b = (const float4*)(nh + (size_t)r.y * D_FEAT);
        float s = 0.f;
#pragma unroll
        for (int q = 0; q < 8; ++q) {
            float4 x = a[q], y = b[q];
            s += x.x * y.x + x.y * y.y + x.z * y.z + x.w * y.w;
        }
        unsigned int u = __float_as_uint(s);
        unsigned int so = (u & 0x80000000u) ? ~u : (u | 0x80000000u);
        unsigned long long key = ((unsigned long long)so << 32) | r.z;
        keys[p] = key;
        atomicAdd(&lh[wave][(unsigned int)(key >> 56)], 1u);
    }
    __syncthreads();
    unsigned int tot = lh[0][t] + lh[1][t] + lh[2][t] + lh[3][t];
    if (tot) atomicAdd(&hist0[t], tot);
}

// compacting radix pass p (1..2). Starts with a redundant scan of hist_prev
// to derive this pass's (prefix,k); block 0 writes the derived state to st_out
// (read only by LATER kernels -> race-free). Filter survivors, histogram next
// digit into hist_cur, compact survivors into the block's private output slice.
__global__ void histc_kernel(const unsigned long long* __restrict__ in,
                             const int* __restrict__ cnt_in,      // null => dense (pass 1)
                             unsigned long long* __restrict__ out,
                             int* __restrict__ cnt_out,
                             const SelState* __restrict__ st_in,  // null => {0, CUT_K}
                             SelState* __restrict__ st_out,
                             const unsigned int* __restrict__ hist_prev,
                             unsigned int* __restrict__ hist_cur, int pass) {
    __shared__ unsigned int lh[4][256];
    __shared__ unsigned int lcnt;
    int t = threadIdx.x, b = blockIdx.x;
#pragma unroll
    for (int w = 0; w < 4; ++w) lh[w][t] = 0u;
    if (t == 0) lcnt = 0u;

    unsigned long long pfx_in = st_in ? st_in->prefix : 0ull;
    unsigned int k_in = st_in ? st_in->k : (unsigned int)CUT_K;
    unsigned int k_cur;
    unsigned long long prefix = scan_select(hist_prev, pfx_in, k_in, &k_cur);
    if (b == 0 && t == 0) { st_out->prefix = prefix; st_out->k = k_cur; }
    __syncthreads();

    int n = cnt_in ? cnt_in[b] : HC_SLICE;
    const unsigned long long* sin = in + (size_t)b * HC_SLICE;
    unsigned long long* sout = out + (size_t)b * HC_SLICE;
    int wave = t >> 6;
    int fshift = 64 - 8 * pass;
    int dshift = 56 - 8 * pass;
    for (int i = t; i < n; i += 256) {
        unsigned long long key = sin[i];
        if ((key >> fshift) == prefix) {
            atomicAdd(&lh[wave][(unsigned int)((key >> dshift) & 0xFFull)], 1u);
            unsigned int slot = atomicAdd(&lcnt, 1u);   // LDS atomic, block-local
            sout[slot] = key;
        }
    }
    __syncthreads();
    if (t == 0) cnt_out[b] = (int)lcnt;
    unsigned int tot = lh[0][t] + lh[1][t] + lh[2][t] + lh[3][t];
    if (tot) atomicAdd(&hist_cur[t], tot);
}

// single-block tail: radix passes 3..7 + final select, entirely in one launch.
// Survivors after 2 passes (16 bits fixed) are ~thousands for this data; each
// pass filters into a dense ping-pong half of `dense` (6.4MB scratch aliasing
// dead nh). Writes the full 64-bit kth key for aggregate to consume.
__global__ void tail_kernel(const unsigned long long* __restrict__ in_sl,
                            const int* __restrict__ cnt_in,
                            unsigned long long* __restrict__ dense,
                            const SelState* __restrict__ st2,
                            const unsigned int* __restrict__ hist2,
                            unsigned long long* __restrict__ kth_out) {
    __shared__ unsigned int lh[256];
    __shared__ unsigned int sbuf[256];
    __shared__ unsigned long long s_pfx;
    __shared__ unsigned int s_k;
    __shared__ unsigned int s_n;
    int t = threadIdx.x;

    unsigned long long pfx = st2->prefix;
    unsigned int k = st2->k;
    {   // select digit 2 from hist2 (global, written by pass 2)
        unsigned int s = hist2[t];
        sbuf[t] = s;
        __syncthreads();
        for (int off = 1; off < 256; off <<= 1) {
            unsigned int v = (t >= off) ? sbuf[t - off] : 0u;
            __syncthreads();
            sbuf[t] += v;
            __syncthreads();
        }
        unsigned int incl = sbuf[t], excl = incl - s;
        if (excl < k && k <= incl) { s_pfx = (pfx << 8) | (unsigned long long)t; s_k = k - excl; }
        __syncthreads();
        pfx = s_pfx; k = s_k;
        __syncthreads();
    }

    unsigned int n_in = 0;
    for (int pass = 3; pass < 8; ++pass) {
        lh[t] = 0u;
        if (t == 0) s_n = 0u;
        __syncthreads();
        int fshift = 64 - 8 * pass;
        int dshift = 56 - 8 * pass;
        unsigned long long* outp = dense + ((pass & 1) ? 0 : TAILCAP);
        if (pass == 3) {
            // input: pass-2 output slices
            for (int b = t; b < HC_NB; b += 256) {
                int n = cnt_in[b];
                const unsigned long long* sl = in_sl + (size_t)b * HC_SLICE;
                for (int i = 0; i < n; ++i) {
                    unsigned long long key = sl[i];
                    if ((key >> fshift) == pfx) {
                        atomicAdd(&lh[(unsigned int)((key >> dshift) & 0xFFull)], 1u);
                        unsigned int slot = atomicAdd(&s_n, 1u);
                        if (slot < TAILCAP) outp[slot] = key;
                    }
                }
            }
        } else {
            const unsigned long long* inp = dense + ((pass & 1) ? TAILCAP : 0);
            for (unsigned int i = t; i < n_in; i += 256) {
                unsigned long long key = inp[i];
                if ((key >> fshift) == pfx) {
                    atomicAdd(&lh[(unsigned int)((key >> dshift) & 0xFFull)], 1u);
                    unsigned int slot = atomicAdd(&s_n, 1u);
                    if (slot < TAILCAP) outp[slot] = key;
                }
            }
        }
        __syncthreads();
        n_in = s_n;
        // select digit `pass` from LDS histogram
        unsigned int s = lh[t];
        sbuf[t] = s;
        __syncthreads();
        for (int off = 1; off < 256; off <<= 1) {
            unsigned int v = (t >= off) ? sbuf[t - off] : 0u;
            __syncthreads();
            sbuf[t] += v;
            __syncthreads();
        }
        unsigned int incl = sbuf[t], excl = incl - s;
        if (excl < k && k <= incl) { s_pfx = (pfx << 8) | (unsigned long long)t; s_k = k - excl; }
        __syncthreads();
        pfx = s_pfx; k = s_k;
        __syncthreads();
    }
    if (t == 0) *kth_out = pfx;    // 8 bytes accumulated == full kth key
}

// pull aggregation: one 32-lane group per node walks its CSR segment.
// kth comes precomputed from tail_kernel (no per-block scan). 8x unrolled
// unconditional gathers for MLP; src from packed uint4 (.x).
__global__ void aggregate_csr_kernel(const float* __restrict__ hs, float* __restrict__ h_out,
                                     const int* __restrict__ offs,
                                     const uint4* __restrict__ csr,
                                     const unsigned long long* __restrict__ keys,
                                     const unsigned long long* __restrict__ kth_in,
                                     const float* __restrict__ nrm, int N) {
    unsigned long long kth = *kth_in;
    int g = blockIdx.x * 8 + (threadIdx.x >> 5);
    int j = threadIdx.x & 31;
    if (g >= N) return;
    int lo = offs[g], hi = offs[g + 1];
    float acc = 0.f;
    int p = lo;
    for (; p + 8 <= hi; p += 8) {
        unsigned long long kk[8];
        unsigned int ss[8];
#pragma unroll
        for (int u = 0; u < 8; ++u) { kk[u] = keys[p + u]; ss[u] = csr[p + u].x; }
        float vv[8];
#pragma unroll
        for (int u = 0; u < 8; ++u) vv[u] = hs[(size_t)ss[u] * D_FEAT + j];
#pragma unroll
        for (int u = 0; u < 8; ++u) acc += (kk[u] > kth) ? vv[u] : 0.f;  // same seq FP order
    }
    for (; p < hi; ++p) {
        if (keys[p] > kth) acc += hs[(size_t)csr[p].x * D_FEAT + j];
    }
    h_out[(size_t)g * D_FEAT + j] = acc * nrm[g];
}

// out = h @ W^T ; stage W transposed in LDS (pad 33, conflict-free)
__global__ void fc_kernel(const float* __restrict__ h, const float* __restrict__ W,
                          float* __restrict__ out, int N) {
    __shared__ float Wt[32][33];
    int t = threadIdx.x;
    for (int i = t; i < 1024; i += 256) Wt[i & 31][i >> 5] = W[i];
    __syncthreads();
    int node = blockIdx.x * 8 + (t >> 5);
    if (node >= N) return;
    int o = t & 31;
    const float* hr = h + (size_t)node * D_FEAT;
    float acc = 0.f;
#pragma unroll
    for (int j = 0; j < 32; ++j) acc += hr[j] * Wt[j][o];
    out[(size_t)node * D_FEAT + o] = acc;
}

extern "C" void kernel_launch(void* const* d_in, const int* in_sizes, int n_in,
                              void* d_out, int out_size, void* d_ws, size_t ws_size,
                              hipStream_t stream) {
    const float* features = (const float*)d_in[0];
    const float* W        = (const float*)d_in[1];
    const int*   src      = (const int*)d_in[2];
    const int*   dst      = (const int*)d_in[3];
    float*       out      = (float*)d_out;

    char* ws = (char*)d_ws;
    size_t o = 0;
    auto take = [&](size_t bytes) -> char* {
        char* p = ws + o;
        o += (bytes + 255) & ~(size_t)255;
        return p;
    };
    int*                deg     = (int*)take((size_t)N_NODES * 4);
    float*              nrm     = (float*)take((size_t)N_NODES * 4);
    int*                offs    = (int*)take((size_t)(N_NODES + 1) * 4);
    int*                cursor  = (int*)take((size_t)N_NODES * 4);
    uint4*              csr     = (uint4*)take((size_t)N_EDGES * 16);
    float*              hA      = (float*)take((size_t)N_NODES * D_FEAT * 4);
    float*              hB      = (float*)take((size_t)N_NODES * D_FEAT * 4);
    float*              nh      = (float*)take((size_t)N_NODES * D_FEAT * 4);
    float*              hs      = (float*)take((size_t)N_NODES * D_FEAT * 4);
    unsigned long long* keys    = (unsigned long long*)take((size_t)N_EDGES * 8);
    unsigned int*       hist    = (unsigned int*)take((size_t)16 * 256 * 4); // per-pass bins
    SelState*           stArr   = (SelState*)take((size_t)16 * sizeof(SelState));
    unsigned long long* kthbuf  = (unsigned long long*)take(256);
    int*                bsum    = (int*)take((size_t)SCAN_NB * 4);
    int*                boff    = (int*)take((size_t)SCAN_NB * 4);
    int*                cnt_a   = (int*)take((size_t)HC_NB * 4);
    int*                cnt_b   = (int*)take((size_t)HC_NB * 4);

    // candidate slice buffers alias dead memory during the radix passes:
    // nh is dead after coskey (pass-1 slices + tail dense scratch);
    // hB is written only by hop-2 aggregate (after selection).
    unsigned long long* candA = (unsigned long long*)nh;
    unsigned long long* candB = (unsigned long long*)hB;

    hipMemsetAsync(deg, 0, (size_t)N_NODES * 4, stream);
    hipMemsetAsync(hist, 0, (size_t)16 * 256 * 4, stream);

    deg_kernel<<<(N_EDGES + 255) / 256, 256, 0, stream>>>(dst, deg, N_EDGES);
    norm_kernel<<<(N_NODES + 255) / 256, 256, 0, stream>>>(deg, nrm, N_NODES);
    blocksum_kernel<<<SCAN_NB, 256, 0, stream>>>(deg, bsum, N_NODES);
    scanpartial_kernel<<<1, 512, 0, stream>>>(bsum, boff, SCAN_NB);
    writeoffs_kernel<<<SCAN_NB, 256, 0, stream>>>(deg, boff, offs, cursor, N_NODES);
    fill_kernel<<<(N_EDGES + 255) / 256, 256, 0, stream>>>(src, dst, cursor, csr, N_EDGES);

    const float* hin = features;
    float* houts[2] = { hA, hB };
    for (int hop = 0; hop < 2; ++hop) {
        float* hout = houts[hop];
        unsigned int* hh = hist + (size_t)hop * 8 * 256;   // per-pass histograms
        SelState*     hst = stArr + (size_t)hop * 8;       // slots [1..2] used
        rownorm_kernel<<<(N_NODES + 255) / 256, 256, 0, stream>>>(hin, nh, hs, nrm, N_NODES);
        coskey_kernel<<<COSKEY_NB, 256, 0, stream>>>(nh, csr, keys, hh, N_EDGES);
        // pass 1: dense keys -> candA slices
        histc_kernel<<<HC_NB, 256, 0, stream>>>(keys, nullptr, candA, cnt_a,
                                                nullptr, hst + 1,
                                                hh + 0 * 256, hh + 1 * 256, 1);
        // pass 2: candA slices -> candB slices
        histc_kernel<<<HC_NB, 256, 0, stream>>>(candA, cnt_a, candB, cnt_b,
                                                hst + 1, hst + 2,
                                                hh + 1 * 256, hh + 2 * 256, 2);
        // passes 3..7 + final select in ONE single-block launch
        tail_kernel<<<1, 256, 0, stream>>>(candB, cnt_b, candA,
                                           hst + 2, hh + 2 * 256, kthbuf + hop);
        aggregate_csr_kernel<<<(N_NODES + 7) / 8, 256, 0, stream>>>(
            hs, hout, offs, csr, keys, kthbuf + hop, nrm, N_NODES);
        hin = hout;
    }
    fc_kernel<<<(N_NODES + 7) / 8, 256, 0, stream>>>(hin, W, out, N_NODES);
}

// Round 6
// 542.607 us; speedup vs baseline: 4.3082x; 1.1915x over previous
//
#include <hip/hip_runtime.h>
#include <hip/hip_bf16.h>
#include <stdint.h>

#define N_NODES 100000
#define N_EDGES 1600000
#define D_FEAT 32
#define CUT_K 320000        // int(N_EDGES * 0.2)
#define COSKEY_NB 4096      // coskey grid: enough blocks for full occupancy
#define HC_NB 1000          // histc blocks; E = HC_NB * HC_SLICE exactly
#define HC_SLICE 1600
#define SCAN_NB ((N_NODES + 255) / 256)   // 391
#define TAILCAP 400000      // tail scratch slots per ping-pong half

struct SelState { unsigned long long prefix; unsigned int k; };

// count in-degrees AND capture each edge's rank within its dst segment
// (the atomicAdd return value we previously discarded). rank[e] is a
// coalesced 4B store; this is what lets fill_kernel be atomic-free.
__global__ void deg_kernel(const int* __restrict__ dst, int* __restrict__ deg,
                           int* __restrict__ rank, int E) {
    int e = blockIdx.x * blockDim.x + threadIdx.x;
    if (e < E) rank[e] = atomicAdd(&deg[dst[e]], 1);
}

// ---- parallel exclusive scan of deg (3 kernels); nrm fused into blocksum ----
__global__ void blocksum_kernel(const int* __restrict__ deg, int* __restrict__ bsum,
                                float* __restrict__ nrm, int N) {
    int i = blockIdx.x * 256 + threadIdx.x;
    int v = (i < N) ? deg[i] : 0;
    if (i < N) nrm[i] = 1.0f / sqrtf(fmaxf((float)v, 1.0f));
#pragma unroll
    for (int off = 32; off > 0; off >>= 1) v += __shfl_down(v, off, 64);
    __shared__ int ws4[4];
    if ((threadIdx.x & 63) == 0) ws4[threadIdx.x >> 6] = v;
    __syncthreads();
    if (threadIdx.x == 0) bsum[blockIdx.x] = ws4[0] + ws4[1] + ws4[2] + ws4[3];
}

__global__ void scanpartial_kernel(const int* __restrict__ bsum, int* __restrict__ boff, int B) {
    __shared__ int buf[512];
    int t = threadIdx.x;
    int v = (t < B) ? bsum[t] : 0;
    buf[t] = v;
    __syncthreads();
    for (int off = 1; off < 512; off <<= 1) {
        int u = (t >= off) ? buf[t - off] : 0;
        __syncthreads();
        buf[t] += u;
        __syncthreads();
    }
    if (t < B) boff[t] = buf[t] - v;   // exclusive
}

__global__ void writeoffs_kernel(const int* __restrict__ deg, const int* __restrict__ boff,
                                 int* __restrict__ offs, int N) {
    __shared__ int buf[256];
    int t = threadIdx.x;
    int i = blockIdx.x * 256 + t;
    int v = (i < N) ? deg[i] : 0;
    buf[t] = v;
    __syncthreads();
    for (int off = 1; off < 256; off <<= 1) {
        int u = (t >= off) ? buf[t - off] : 0;
        __syncthreads();
        buf[t] += u;
        __syncthreads();
    }
    int ex = buf[t] - v + boff[blockIdx.x];
    if (i < N) offs[i] = ex;
    if (i == N - 1) offs[N] = ex + v;   // == E
}

// ATOMIC-FREE scatter into CSR-by-dst slots: pos = offs[dst] + rank (rank was
// captured in deg_kernel). r4 post-mortem: fill was bound by the contended
// atomicAdd round-trip (145us at only 770GB/s, store-count didn't matter).
// Now the chain is coalesced loads -> L2 offs gather -> one uint4 store.
__global__ void fill_kernel(const int* __restrict__ src, const int* __restrict__ dst,
                            const int* __restrict__ rank, const int* __restrict__ offs,
                            uint4* __restrict__ csr, int E) {
    int e = blockIdx.x * blockDim.x + threadIdx.x;
    if (e >= E) return;
    int d = dst[e];
    int pos = offs[d] + rank[e];
    csr[pos] = make_uint4((unsigned int)src[e], (unsigned int)d, (unsigned int)e, 0u);
}

// nh = h / max(||h||,1e-12)  AND  hs = h * nrm  (fused)
__global__ void rownorm_kernel(const float* __restrict__ h, float* __restrict__ nh,
                               float* __restrict__ hs, const float* __restrict__ nrm,
                               int N) {
    int i = blockIdx.x * blockDim.x + threadIdx.x;
    if (i >= N) return;
    const float4* hp = (const float4*)(h + (size_t)i * D_FEAT);
    float4 v[8];
    float ss = 0.f;
#pragma unroll
    for (int q = 0; q < 8; ++q) {
        v[q] = hp[q];
        ss += v[q].x * v[q].x + v[q].y * v[q].y + v[q].z * v[q].z + v[q].w * v[q].w;
    }
    float inv = 1.0f / fmaxf(sqrtf(ss), 1e-12f);
    float sc = nrm[i];
    float4* op = (float4*)(nh + (size_t)i * D_FEAT);
    float4* sp = (float4*)(hs + (size_t)i * D_FEAT);
#pragma unroll
    for (int q = 0; q < 8; ++q) {
        float4 ov = v[q];
        float4 sv = v[q];
        ov.x *= inv; ov.y *= inv; ov.z *= inv; ov.w *= inv;
        sv.x *= sc;  sv.y *= sc;  sv.z *= sc;  sv.w *= sc;
        op[q] = ov;
        sp[q] = sv;
    }
}

// Redundant per-block 256-bin scan/select (reads the PREVIOUS kernel's
// histogram — visible via stream ordering, no fences). All 256 threads.
__device__ __forceinline__ unsigned long long scan_select(
        const unsigned int* __restrict__ hist,
        unsigned long long pfx_in, unsigned int k_in,
        unsigned int* k_out) {
    __shared__ unsigned int sbuf[256];
    __shared__ unsigned long long s_pfx;
    __shared__ unsigned int s_k;
    int t = threadIdx.x;
    unsigned int s = hist[t];
    sbuf[t] = s;
    __syncthreads();
    for (int off = 1; off < 256; off <<= 1) {
        unsigned int v = (t >= off) ? sbuf[t - off] : 0u;
        __syncthreads();
        sbuf[t] += v;
        __syncthreads();
    }
    unsigned int incl = sbuf[t];
    unsigned int excl = incl - s;
    if (excl < k_in && k_in <= incl) {          // exactly one thread wins
        s_pfx = (pfx_in << 8) | (unsigned long long)t;
        s_k = k_in - excl;
    }
    __syncthreads();
    if (k_out) *k_out = s_k;
    return s_pfx;
}

// edge-parallel cos keys (grid-stride, full occupancy + MLP). CSR order makes
// consecutive p share the same dst row -> b-gathers are L1/L2 hits. Fused
// digit-0 histogram into hist0.
__global__ void coskey_kernel(const float* __restrict__ nh, const uint4* __restrict__ csr,
                              unsigned long long* __restrict__ keys,
                              unsigned int* __restrict__ hist0, int E) {
    __shared__ unsigned int lh[4][256];
    int t = threadIdx.x;
#pragma unroll
    for (int w = 0; w < 4; ++w) lh[w][t] = 0u;
    __syncthreads();
    int wave = t >> 6;
    int stride = gridDim.x * blockDim.x;
    for (int p = blockIdx.x * blockDim.x + t; p < E; p += stride) {
        uint4 r = csr[p];   // x=src, y=dst, z=eid
        const float4* a = (const float4*)(nh + (size_t)r.x * D_FEAT);
        const float4* b = (const float4*)(nh + (size_t)r.y * D_FEAT);
        float s = 0.f;
#pragma unroll
        for (int q = 0; q < 8; ++q) {
            float4 x = a[q], y = b[q];
            s += x.x * y.x + x.y * y.y + x.z * y.z + x.w * y.w;
        }
        unsigned int u = __float_as_uint(s);
        unsigned int so = (u & 0x80000000u) ? ~u : (u | 0x80000000u);
        unsigned long long key = ((unsigned long long)so << 32) | r.z;
        keys[p] = key;
        atomicAdd(&lh[wave][(unsigned int)(key >> 56)], 1u);
    }
    __syncthreads();
    unsigned int tot = lh[0][t] + lh[1][t] + lh[2][t] + lh[3][t];
    if (tot) atomicAdd(&hist0[t], tot);
}

// compacting radix pass p (1..2). Redundant scan of hist_prev derives
// (prefix,k); block 0 persists it to st_out (read only by later kernels).
__global__ void histc_kernel(const unsigned long long* __restrict__ in,
                             const int* __restrict__ cnt_in,      // null => dense (pass 1)
                             unsigned long long* __restrict__ out,
                             int* __restrict__ cnt_out,
                             const SelState* __restrict__ st_in,  // null => {0, CUT_K}
                             SelState* __restrict__ st_out,
                             const unsigned int* __restrict__ hist_prev,
                             unsigned int* __restrict__ hist_cur, int pass) {
    __shared__ unsigned int lh[4][256];
    __shared__ unsigned int lcnt;
    int t = threadIdx.x, b = blockIdx.x;
#pragma unroll
    for (int w = 0; w < 4; ++w) lh[w][t] = 0u;
    if (t == 0) lcnt = 0u;

    unsigned long long pfx_in = st_in ? st_in->prefix : 0ull;
    unsigned int k_in = st_in ? st_in->k : (unsigned int)CUT_K;
    unsigned int k_cur;
    unsigned long long prefix = scan_select(hist_prev, pfx_in, k_in, &k_cur);
    if (b == 0 && t == 0) { st_out->prefix = prefix; st_out->k = k_cur; }
    __syncthreads();

    int n = cnt_in ? cnt_in[b] : HC_SLICE;
    const unsigned long long* sin = in + (size_t)b * HC_SLICE;
    unsigned long long* sout = out + (size_t)b * HC_SLICE;
    int wave = t >> 6;
    int fshift = 64 - 8 * pass;
    int dshift = 56 - 8 * pass;
    for (int i = t; i < n; i += 256) {
        unsigned long long key = sin[i];
        if ((key >> fshift) == prefix) {
            atomicAdd(&lh[wave][(unsigned int)((key >> dshift) & 0xFFull)], 1u);
            unsigned int slot = atomicAdd(&lcnt, 1u);   // LDS atomic, block-local
            sout[slot] = key;
        }
    }
    __syncthreads();
    if (t == 0) cnt_out[b] = (int)lcnt;
    unsigned int tot = lh[0][t] + lh[1][t] + lh[2][t] + lh[3][t];
    if (tot) atomicAdd(&hist_cur[t], tot);
}

// single-block tail: radix passes 3..7 + final select, entirely in one launch.
// Survivors after 2 passes (16 bits fixed) are ~thousands; ping-pong through
// dense scratch (aliasing dead nh). Emits the full 64-bit kth key.
__global__ void tail_kernel(const unsigned long long* __restrict__ in_sl,
                            const int* __restrict__ cnt_in,
                            unsigned long long* __restrict__ dense,
                            const SelState* __restrict__ st2,
                            const unsigned int* __restrict__ hist2,
                            unsigned long long* __restrict__ kth_out) {
    __shared__ unsigned int lh[256];
    __shared__ unsigned int sbuf[256];
    __shared__ unsigned long long s_pfx;
    __shared__ unsigned int s_k;
    __shared__ unsigned int s_n;
    int t = threadIdx.x;

    unsigned long long pfx = st2->prefix;
    unsigned int k = st2->k;
    {   // select digit 2 from hist2 (global, written by pass 2)
        unsigned int s = hist2[t];
        sbuf[t] = s;
        __syncthreads();
        for (int off = 1; off < 256; off <<= 1) {
            unsigned int v = (t >= off) ? sbuf[t - off] : 0u;
            __syncthreads();
            sbuf[t] += v;
            __syncthreads();
        }
        unsigned int incl = sbuf[t], excl = incl - s;
        if (excl < k && k <= incl) { s_pfx = (pfx << 8) | (unsigned long long)t; s_k = k - excl; }
        __syncthreads();
        pfx = s_pfx; k = s_k;
        __syncthreads();
    }

    unsigned int n_in = 0;
    for (int pass = 3; pass < 8; ++pass) {
        lh[t] = 0u;
        if (t == 0) s_n = 0u;
        __syncthreads();
        int fshift = 64 - 8 * pass;
        int dshift = 56 - 8 * pass;
        unsigned long long* outp = dense + ((pass & 1) ? 0 : TAILCAP);
        if (pass == 3) {
            // input: pass-2 output slices
            for (int b = t; b < HC_NB; b += 256) {
                int n = cnt_in[b];
                const unsigned long long* sl = in_sl + (size_t)b * HC_SLICE;
                for (int i = 0; i < n; ++i) {
                    unsigned long long key = sl[i];
                    if ((key >> fshift) == pfx) {
                        atomicAdd(&lh[(unsigned int)((key >> dshift) & 0xFFull)], 1u);
                        unsigned int slot = atomicAdd(&s_n, 1u);
                        if (slot < TAILCAP) outp[slot] = key;
                    }
                }
            }
        } else {
            const unsigned long long* inp = dense + ((pass & 1) ? TAILCAP : 0);
            for (unsigned int i = t; i < n_in; i += 256) {
                unsigned long long key = inp[i];
                if ((key >> fshift) == pfx) {
                    atomicAdd(&lh[(unsigned int)((key >> dshift) & 0xFFull)], 1u);
                    unsigned int slot = atomicAdd(&s_n, 1u);
                    if (slot < TAILCAP) outp[slot] = key;
                }
            }
        }
        __syncthreads();
        n_in = s_n;
        // select digit `pass` from LDS histogram
        unsigned int s = lh[t];
        sbuf[t] = s;
        __syncthreads();
        for (int off = 1; off < 256; off <<= 1) {
            unsigned int v = (t >= off) ? sbuf[t - off] : 0u;
            __syncthreads();
            sbuf[t] += v;
            __syncthreads();
        }
        unsigned int incl = sbuf[t], excl = incl - s;
        if (excl < k && k <= incl) { s_pfx = (pfx << 8) | (unsigned long long)t; s_k = k - excl; }
        __syncthreads();
        pfx = s_pfx; k = s_k;
        __syncthreads();
    }
    if (t == 0) *kth_out = pfx;    // 8 bytes accumulated == full kth key
}

// pull aggregation: one 32-lane group per node walks its CSR segment.
// kth comes precomputed from tail_kernel. 8x unrolled unconditional gathers.
__global__ void aggregate_csr_kernel(const float* __restrict__ hs, float* __restrict__ h_out,
                                     const int* __restrict__ offs,
                                     const uint4* __restrict__ csr,
                                     const unsigned long long* __restrict__ keys,
                                     const unsigned long long* __restrict__ kth_in,
                                     const float* __restrict__ nrm, int N) {
    unsigned long long kth = *kth_in;
    int g = blockIdx.x * 8 + (threadIdx.x >> 5);
    int j = threadIdx.x & 31;
    if (g >= N) return;
    int lo = offs[g], hi = offs[g + 1];
    float acc = 0.f;
    int p = lo;
    for (; p + 8 <= hi; p += 8) {
        unsigned long long kk[8];
        unsigned int ss[8];
#pragma unroll
        for (int u = 0; u < 8; ++u) { kk[u] = keys[p + u]; ss[u] = csr[p + u].x; }
        float vv[8];
#pragma unroll
        for (int u = 0; u < 8; ++u) vv[u] = hs[(size_t)ss[u] * D_FEAT + j];
#pragma unroll
        for (int u = 0; u < 8; ++u) acc += (kk[u] > kth) ? vv[u] : 0.f;  // same seq FP order
    }
    for (; p < hi; ++p) {
        if (keys[p] > kth) acc += hs[(size_t)csr[p].x * D_FEAT + j];
    }
    h_out[(size_t)g * D_FEAT + j] = acc * nrm[g];
}

// out = h @ W^T ; stage W transposed in LDS (pad 33, conflict-free)
__global__ void fc_kernel(const float* __restrict__ h, const float* __restrict__ W,
                          float* __restrict__ out, int N) {
    __shared__ float Wt[32][33];
    int t = threadIdx.x;
    for (int i = t; i < 1024; i += 256) Wt[i & 31][i >> 5] = W[i];
    __syncthreads();
    int node = blockIdx.x * 8 + (t >> 5);
    if (node >= N) return;
    int o = t & 31;
    const float* hr = h + (size_t)node * D_FEAT;
    float acc = 0.f;
#pragma unroll
    for (int j = 0; j < 32; ++j) acc += hr[j] * Wt[j][o];
    out[(size_t)node * D_FEAT + o] = acc;
}

extern "C" void kernel_launch(void* const* d_in, const int* in_sizes, int n_in,
                              void* d_out, int out_size, void* d_ws, size_t ws_size,
                              hipStream_t stream) {
    const float* features = (const float*)d_in[0];
    const float* W        = (const float*)d_in[1];
    const int*   src      = (const int*)d_in[2];
    const int*   dst      = (const int*)d_in[3];
    float*       out      = (float*)d_out;

    char* ws = (char*)d_ws;
    size_t o = 0;
    auto take = [&](size_t bytes) -> char* {
        char* p = ws + o;
        o += (bytes + 255) & ~(size_t)255;
        return p;
    };
    int*                deg     = (int*)take((size_t)N_NODES * 4);
    float*              nrm     = (float*)take((size_t)N_NODES * 4);
    int*                offs    = (int*)take((size_t)(N_NODES + 1) * 4);
    int*                rank    = (int*)take((size_t)N_EDGES * 4);
    uint4*              csr     = (uint4*)take((size_t)N_EDGES * 16);
    float*              hA      = (float*)take((size_t)N_NODES * D_FEAT * 4);
    float*              hB      = (float*)take((size_t)N_NODES * D_FEAT * 4);
    float*              nh      = (float*)take((size_t)N_NODES * D_FEAT * 4);
    float*              hs      = (float*)take((size_t)N_NODES * D_FEAT * 4);
    unsigned long long* keys    = (unsigned long long*)take((size_t)N_EDGES * 8);
    unsigned int*       hist    = (unsigned int*)take((size_t)16 * 256 * 4); // per-pass bins
    SelState*           stArr   = (SelState*)take((size_t)16 * sizeof(SelState));
    unsigned long long* kthbuf  = (unsigned long long*)take(256);
    int*                bsum    = (int*)take((size_t)SCAN_NB * 4);
    int*                boff    = (int*)take((size_t)SCAN_NB * 4);
    int*                cnt_a   = (int*)take((size_t)HC_NB * 4);
    int*                cnt_b   = (int*)take((size_t)HC_NB * 4);

    // candidate slice buffers alias dead memory during the radix passes:
    // nh is dead after coskey (pass-1 slices + tail dense scratch);
    // hB is written only by hop-2 aggregate (after selection).
    unsigned long long* candA = (unsigned long long*)nh;
    unsigned long long* candB = (unsigned long long*)hB;

    hipMemsetAsync(deg, 0, (size_t)N_NODES * 4, stream);
    hipMemsetAsync(hist, 0, (size_t)16 * 256 * 4, stream);

    deg_kernel<<<(N_EDGES + 255) / 256, 256, 0, stream>>>(dst, deg, rank, N_EDGES);
    blocksum_kernel<<<SCAN_NB, 256, 0, stream>>>(deg, bsum, nrm, N_NODES);
    scanpartial_kernel<<<1, 512, 0, stream>>>(bsum, boff, SCAN_NB);
    writeoffs_kernel<<<SCAN_NB, 256, 0, stream>>>(deg, boff, offs, N_NODES);
    fill_kernel<<<(N_EDGES + 255) / 256, 256, 0, stream>>>(src, dst, rank, offs, csr, N_EDGES);

    const float* hin = features;
    float* houts[2] = { hA, hB };
    for (int hop = 0; hop < 2; ++hop) {
        float* hout = houts[hop];
        unsigned int* hh = hist + (size_t)hop * 8 * 256;   // per-pass histograms
        SelState*     hst = stArr + (size_t)hop * 8;       // slots [1..2] used
        rownorm_kernel<<<(N_NODES + 255) / 256, 256, 0, stream>>>(hin, nh, hs, nrm, N_NODES);
        coskey_kernel<<<COSKEY_NB, 256, 0, stream>>>(nh, csr, keys, hh, N_EDGES);
        // pass 1: dense keys -> candA slices
        histc_kernel<<<HC_NB, 256, 0, stream>>>(keys, nullptr, candA, cnt_a,
                                                nullptr, hst + 1,
                                                hh + 0 * 256, hh + 1 * 256, 1);
        // pass 2: candA slices -> candB slices
        histc_kernel<<<HC_NB, 256, 0, stream>>>(candA, cnt_a, candB, cnt_b,
                                                hst + 1, hst + 2,
                                                hh + 1 * 256, hh + 2 * 256, 2);
        // passes 3..7 + final select in ONE single-block launch
        tail_kernel<<<1, 256, 0, stream>>>(candB, cnt_b, candA,
                                           hst + 2, hh + 2 * 256, kthbuf + hop);
        aggregate_csr_kernel<<<(N_NODES + 7) / 8, 256, 0, stream>>>(
            hs, hout, offs, csr, keys, kthbuf + hop, nrm, N_NODES);
        hin = hout;
    }
    fc_kernel<<<(N_NODES + 7) / 8, 256, 0, stream>>>(hin, W, out, N_NODES);
}

// Round 7
// 508.098 us; speedup vs baseline: 4.6008x; 1.0679x over previous
//
#include <hip/hip_runtime.h>
#include <hip/hip_bf16.h>
#include <stdint.h>

#define N_NODES 100000
#define N_EDGES 1600000
#define D_FEAT 32
#define CUT_K 320000        // int(N_EDGES * 0.2)
#define COSKEY_NB 3125      // 2 edges/thread: 3125*256*2 == N_EDGES exactly
#define HC_NB 1000          // histc blocks; E = HC_NB * HC_SLICE exactly
#define HC_SLICE 1600
#define SCAN_NB ((N_NODES + 255) / 256)   // 391
#define TAILCAP 400000      // tail scratch slots per ping-pong half

struct SelState { unsigned long long prefix; unsigned int k; };

// count in-degrees AND capture each edge's rank within its dst segment
// (the atomicAdd return value). rank[e] is coalesced; fill is atomic-free.
__global__ void deg_kernel(const int* __restrict__ dst, int* __restrict__ deg,
                           int* __restrict__ rank, int E) {
    int e = blockIdx.x * blockDim.x + threadIdx.x;
    if (e < E) rank[e] = atomicAdd(&deg[dst[e]], 1);
}

// per-256-chunk sums of deg; nrm fused (reads deg anyway)
__global__ void blocksum_kernel(const int* __restrict__ deg, int* __restrict__ bsum,
                                float* __restrict__ nrm, int N) {
    int i = blockIdx.x * 256 + threadIdx.x;
    int v = (i < N) ? deg[i] : 0;
    if (i < N) nrm[i] = 1.0f / sqrtf(fmaxf((float)v, 1.0f));
#pragma unroll
    for (int off = 32; off > 0; off >>= 1) v += __shfl_down(v, off, 64);
    __shared__ int ws4[4];
    if ((threadIdx.x & 63) == 0) ws4[threadIdx.x >> 6] = v;
    __syncthreads();
    if (threadIdx.x == 0) bsum[blockIdx.x] = ws4[0] + ws4[1] + ws4[2] + ws4[3];
}

// writeoffs with the block-offset reduction folded in: each block redundantly
// sums bsum[0..blockIdx) (<=391 ints, L2-hot) — removes the scanpartial launch.
__global__ void writeoffs_kernel(const int* __restrict__ deg, const int* __restrict__ bsum,
                                 int* __restrict__ offs, int N) {
    __shared__ int buf[256];
    __shared__ int ws4[4];
    __shared__ int sboff;
    int t = threadIdx.x;
    int b = blockIdx.x;
    int partial = 0;
    for (int i = t; i < b; i += 256) partial += bsum[i];
#pragma unroll
    for (int off = 32; off > 0; off >>= 1) partial += __shfl_down(partial, off, 64);
    if ((t & 63) == 0) ws4[t >> 6] = partial;
    __syncthreads();
    if (t == 0) sboff = ws4[0] + ws4[1] + ws4[2] + ws4[3];
    __syncthreads();
    int i = b * 256 + t;
    int v = (i < N) ? deg[i] : 0;
    buf[t] = v;
    __syncthreads();
    for (int off = 1; off < 256; off <<= 1) {
        int u = (t >= off) ? buf[t - off] : 0;
        __syncthreads();
        buf[t] += u;
        __syncthreads();
    }
    int ex = buf[t] - v + sboff;
    if (i < N) offs[i] = ex;
    if (i == N - 1) offs[N] = ex + v;   // == E
}

// ATOMIC-FREE scatter into CSR-by-dst slots: pos = offs[dst] + rank.
__global__ void fill_kernel(const int* __restrict__ src, const int* __restrict__ dst,
                            const int* __restrict__ rank, const int* __restrict__ offs,
                            uint4* __restrict__ csr, int E) {
    int e = blockIdx.x * blockDim.x + threadIdx.x;
    if (e >= E) return;
    int d = dst[e];
    int pos = offs[d] + rank[e];
    csr[pos] = make_uint4((unsigned int)src[e], (unsigned int)d, (unsigned int)e, 0u);
}

// nh = h / max(||h||,1e-12) only (hs removed: aggregate computes h*nrm inline,
// bit-identical fl(h*nrm), saving a 12.8MB write here)
__global__ void rownorm_kernel(const float* __restrict__ h, float* __restrict__ nh, int N) {
    int i = blockIdx.x * blockDim.x + threadIdx.x;
    if (i >= N) return;
    const float4* hp = (const float4*)(h + (size_t)i * D_FEAT);
    float4 v[8];
    float ss = 0.f;
#pragma unroll
    for (int q = 0; q < 8; ++q) {
        v[q] = hp[q];
        ss += v[q].x * v[q].x + v[q].y * v[q].y + v[q].z * v[q].z + v[q].w * v[q].w;
    }
    float inv = 1.0f / fmaxf(sqrtf(ss), 1e-12f);
    float4* op = (float4*)(nh + (size_t)i * D_FEAT);
#pragma unroll
    for (int q = 0; q < 8; ++q) {
        float4 ov = v[q];
        ov.x *= inv; ov.y *= inv; ov.z *= inv; ov.w *= inv;
        op[q] = ov;
    }
}

// Redundant per-block 256-bin scan/select (reads the PREVIOUS kernel's
// histogram — visible via stream ordering, no fences). All 256 threads.
__device__ __forceinline__ unsigned long long scan_select(
        const unsigned int* __restrict__ hist,
        unsigned long long pfx_in, unsigned int k_in,
        unsigned int* k_out) {
    __shared__ unsigned int sbuf[256];
    __shared__ unsigned long long s_pfx;
    __shared__ unsigned int s_k;
    int t = threadIdx.x;
    unsigned int s = hist[t];
    sbuf[t] = s;
    __syncthreads();
    for (int off = 1; off < 256; off <<= 1) {
        unsigned int v = (t >= off) ? sbuf[t - off] : 0u;
        __syncthreads();
        sbuf[t] += v;
        __syncthreads();
    }
    unsigned int incl = sbuf[t];
    unsigned int excl = incl - s;
    if (excl < k_in && k_in <= incl) {          // exactly one thread wins
        s_pfx = (pfx_in << 8) | (unsigned long long)t;
        s_k = k_in - excl;
    }
    __syncthreads();
    if (k_out) *k_out = s_k;
    return s_pfx;
}

// edge-parallel cos keys, 2 CONSECUTIVE edges per thread: doubles outstanding
// row-gathers per thread (kernel is gather-latency-bound: FETCH ~= 1 L2-miss
// line per edge, VALUBusy <1%). Consecutive pair usually shares the dst row
// (L1 hit). Per-edge dot order is UNCHANGED (selection-critical rounding).
// Keys stored as one ulonglong2 (16B coalesced).
__global__ void coskey_kernel(const float* __restrict__ nh, const uint4* __restrict__ csr,
                              unsigned long long* __restrict__ keys,
                              unsigned int* __restrict__ hist0, int E) {
    __shared__ unsigned int lh[4][256];
    int t = threadIdx.x;
#pragma unroll
    for (int w = 0; w < 4; ++w) lh[w][t] = 0u;
    __syncthreads();
    int wave = t >> 6;
    int p0 = (blockIdx.x * 256 + t) * 2;      // p0+1 < E by construction
    uint4 r0 = csr[p0];
    uint4 r1 = csr[p0 + 1];
    const float4* a0 = (const float4*)(nh + (size_t)r0.x * D_FEAT);
    const float4* b0 = (const float4*)(nh + (size_t)r0.y * D_FEAT);
    const float4* a1 = (const float4*)(nh + (size_t)r1.x * D_FEAT);
    const float4* b1 = (const float4*)(nh + (size_t)r1.y * D_FEAT);
    float s0 = 0.f, s1 = 0.f;
#pragma unroll
    for (int q = 0; q < 8; ++q) {
        float4 x0 = a0[q], y0 = b0[q];
        s0 += x0.x * y0.x + x0.y * y0.y + x0.z * y0.z + x0.w * y0.w;
        float4 x1 = a1[q], y1 = b1[q];
        s1 += x1.x * y1.x + x1.y * y1.y + x1.z * y1.z + x1.w * y1.w;
    }
    unsigned int u0 = __float_as_uint(s0);
    unsigned int so0 = (u0 & 0x80000000u) ? ~u0 : (u0 | 0x80000000u);
    unsigned long long k0 = ((unsigned long long)so0 << 32) | r0.z;
    unsigned int u1 = __float_as_uint(s1);
    unsigned int so1 = (u1 & 0x80000000u) ? ~u1 : (u1 | 0x80000000u);
    unsigned long long k1 = ((unsigned long long)so1 << 32) | r1.z;
    *(ulonglong2*)(keys + p0) = make_ulonglong2(k0, k1);
    atomicAdd(&lh[wave][(unsigned int)(k0 >> 56)], 1u);
    atomicAdd(&lh[wave][(unsigned int)(k1 >> 56)], 1u);
    __syncthreads();
    unsigned int tot = lh[0][t] + lh[1][t] + lh[2][t] + lh[3][t];
    if (tot) atomicAdd(&hist0[t], tot);
}

// compacting radix pass p (1..2). Redundant scan of hist_prev derives
// (prefix,k); block 0 persists it to st_out (read only by later kernels).
__global__ void histc_kernel(const unsigned long long* __restrict__ in,
                             const int* __restrict__ cnt_in,      // null => dense (pass 1)
                             unsigned long long* __restrict__ out,
                             int* __restrict__ cnt_out,
                             const SelState* __restrict__ st_in,  // null => {0, CUT_K}
                             SelState* __restrict__ st_out,
                             const unsigned int* __restrict__ hist_prev,
                             unsigned int* __restrict__ hist_cur, int pass) {
    __shared__ unsigned int lh[4][256];
    __shared__ unsigned int lcnt;
    int t = threadIdx.x, b = blockIdx.x;
#pragma unroll
    for (int w = 0; w < 4; ++w) lh[w][t] = 0u;
    if (t == 0) lcnt = 0u;

    unsigned long long pfx_in = st_in ? st_in->prefix : 0ull;
    unsigned int k_in = st_in ? st_in->k : (unsigned int)CUT_K;
    unsigned int k_cur;
    unsigned long long prefix = scan_select(hist_prev, pfx_in, k_in, &k_cur);
    if (b == 0 && t == 0) { st_out->prefix = prefix; st_out->k = k_cur; }
    __syncthreads();

    int n = cnt_in ? cnt_in[b] : HC_SLICE;
    const unsigned long long* sin = in + (size_t)b * HC_SLICE;
    unsigned long long* sout = out + (size_t)b * HC_SLICE;
    int wave = t >> 6;
    int fshift = 64 - 8 * pass;
    int dshift = 56 - 8 * pass;
    for (int i = t; i < n; i += 256) {
        unsigned long long key = sin[i];
        if ((key >> fshift) == prefix) {
            atomicAdd(&lh[wave][(unsigned int)((key >> dshift) & 0xFFull)], 1u);
            unsigned int slot = atomicAdd(&lcnt, 1u);   // LDS atomic, block-local
            sout[slot] = key;
        }
    }
    __syncthreads();
    if (t == 0) cnt_out[b] = (int)lcnt;
    unsigned int tot = lh[0][t] + lh[1][t] + lh[2][t] + lh[3][t];
    if (tot) atomicAdd(&hist_cur[t], tot);
}

// single-block tail: radix passes 3..7 + final select, one launch.
__global__ void tail_kernel(const unsigned long long* __restrict__ in_sl,
                            const int* __restrict__ cnt_in,
                            unsigned long long* __restrict__ dense,
                            const SelState* __restrict__ st2,
                            const unsigned int* __restrict__ hist2,
                            unsigned long long* __restrict__ kth_out) {
    __shared__ unsigned int lh[256];
    __shared__ unsigned int sbuf[256];
    __shared__ unsigned long long s_pfx;
    __shared__ unsigned int s_k;
    __shared__ unsigned int s_n;
    int t = threadIdx.x;

    unsigned long long pfx = st2->prefix;
    unsigned int k = st2->k;
    {   // select digit 2 from hist2 (global, written by pass 2)
        unsigned int s = hist2[t];
        sbuf[t] = s;
        __syncthreads();
        for (int off = 1; off < 256; off <<= 1) {
            unsigned int v = (t >= off) ? sbuf[t - off] : 0u;
            __syncthreads();
            sbuf[t] += v;
            __syncthreads();
        }
        unsigned int incl = sbuf[t], excl = incl - s;
        if (excl < k && k <= incl) { s_pfx = (pfx << 8) | (unsigned long long)t; s_k = k - excl; }
        __syncthreads();
        pfx = s_pfx; k = s_k;
        __syncthreads();
    }

    unsigned int n_in = 0;
    for (int pass = 3; pass < 8; ++pass) {
        lh[t] = 0u;
        if (t == 0) s_n = 0u;
        __syncthreads();
        int fshift = 64 - 8 * pass;
        int dshift = 56 - 8 * pass;
        unsigned long long* outp = dense + ((pass & 1) ? 0 : TAILCAP);
        if (pass == 3) {
            for (int b = t; b < HC_NB; b += 256) {
                int n = cnt_in[b];
                const unsigned long long* sl = in_sl + (size_t)b * HC_SLICE;
                for (int i = 0; i < n; ++i) {
                    unsigned long long key = sl[i];
                    if ((key >> fshift) == pfx) {
                        atomicAdd(&lh[(unsigned int)((key >> dshift) & 0xFFull)], 1u);
                        unsigned int slot = atomicAdd(&s_n, 1u);
                        if (slot < TAILCAP) outp[slot] = key;
                    }
                }
            }
        } else {
            const unsigned long long* inp = dense + ((pass & 1) ? TAILCAP : 0);
            for (unsigned int i = t; i < n_in; i += 256) {
                unsigned long long key = inp[i];
                if ((key >> fshift) == pfx) {
                    atomicAdd(&lh[(unsigned int)((key >> dshift) & 0xFFull)], 1u);
                    unsigned int slot = atomicAdd(&s_n, 1u);
                    if (slot < TAILCAP) outp[slot] = key;
                }
            }
        }
        __syncthreads();
        n_in = s_n;
        unsigned int s = lh[t];
        sbuf[t] = s;
        __syncthreads();
        for (int off = 1; off < 256; off <<= 1) {
            unsigned int v = (t >= off) ? sbuf[t - off] : 0u;
            __syncthreads();
            sbuf[t] += v;
            __syncthreads();
        }
        unsigned int incl = sbuf[t], excl = incl - s;
        if (excl < k && k <= incl) { s_pfx = (pfx << 8) | (unsigned long long)t; s_k = k - excl; }
        __syncthreads();
        pfx = s_pfx; k = s_k;
        __syncthreads();
    }
    if (t == 0) *kth_out = pfx;    // full 64-bit kth key
}

// pull aggregation: one 32-lane group per node walks its CSR segment.
// Gathers RAW h and multiplies by nrm[src] inline: fl(h*nrm) is bit-identical
// to the old staged hs element. FUSE_FC: hop-2 applies W via LDS (grid is
// exactly N/8 full blocks, so barriers are uniform; j-sequential dot order
// identical to the old fc_kernel).
template<bool FUSE_FC>
__global__ void aggregate_csr_kernel(const float* __restrict__ h_in, float* __restrict__ h_out,
                                     const int* __restrict__ offs,
                                     const uint4* __restrict__ csr,
                                     const unsigned long long* __restrict__ keys,
                                     const unsigned long long* __restrict__ kth_in,
                                     const float* __restrict__ nrm,
                                     const float* __restrict__ W, int N) {
    __shared__ float Ws[32][33];
    __shared__ float hrow[8][33];
    int t = threadIdx.x;
    if (FUSE_FC) {
        for (int i = t; i < 1024; i += 256) Ws[i >> 5][i & 31] = W[i];  // Ws[o][j]
        __syncthreads();
    }
    unsigned long long kth = *kth_in;
    int g = blockIdx.x * 8 + (t >> 5);
    int j = t & 31;
    if (!FUSE_FC && g >= N) return;    // grid is exact; guard kept for safety
    int lo = offs[g], hi = offs[g + 1];
    float acc = 0.f;
    int p = lo;
    for (; p + 8 <= hi; p += 8) {
        unsigned long long kk[8];
        unsigned int ss[8];
#pragma unroll
        for (int u = 0; u < 8; ++u) { kk[u] = keys[p + u]; ss[u] = csr[p + u].x; }
        float vv[8];
#pragma unroll
        for (int u = 0; u < 8; ++u) vv[u] = h_in[(size_t)ss[u] * D_FEAT + j] * nrm[ss[u]];
#pragma unroll
        for (int u = 0; u < 8; ++u) acc += (kk[u] > kth) ? vv[u] : 0.f;  // same seq FP order
    }
    for (; p < hi; ++p) {
        if (keys[p] > kth) {
            unsigned int s = csr[p].x;
            acc += h_in[(size_t)s * D_FEAT + j] * nrm[s];
        }
    }
    float val = acc * nrm[g];
    if (!FUSE_FC) {
        h_out[(size_t)g * D_FEAT + j] = val;
        return;
    }
    hrow[t >> 5][j] = val;
    __syncthreads();
    float oacc = 0.f;
#pragma unroll
    for (int q = 0; q < 32; ++q) oacc += hrow[t >> 5][q] * Ws[j][q];   // lane j == out feat
    h_out[(size_t)g * D_FEAT + j] = oacc;
}

extern "C" void kernel_launch(void* const* d_in, const int* in_sizes, int n_in,
                              void* d_out, int out_size, void* d_ws, size_t ws_size,
                              hipStream_t stream) {
    const float* features = (const float*)d_in[0];
    const float* W        = (const float*)d_in[1];
    const int*   src      = (const int*)d_in[2];
    const int*   dst      = (const int*)d_in[3];
    float*       out      = (float*)d_out;

    char* ws = (char*)d_ws;
    size_t o = 0;
    auto take = [&](size_t bytes) -> char* {
        char* p = ws + o;
        o += (bytes + 255) & ~(size_t)255;
        return p;
    };
    int*                deg     = (int*)take((size_t)N_NODES * 4);
    float*              nrm     = (float*)take((size_t)N_NODES * 4);
    int*                offs    = (int*)take((size_t)(N_NODES + 1) * 4);
    int*                rank    = (int*)take((size_t)N_EDGES * 4);
    uint4*              csr     = (uint4*)take((size_t)N_EDGES * 16);
    float*              hA      = (float*)take((size_t)N_NODES * D_FEAT * 4);
    float*              hB      = (float*)take((size_t)N_NODES * D_FEAT * 4);
    float*              nh      = (float*)take((size_t)N_NODES * D_FEAT * 4);
    unsigned long long* keys    = (unsigned long long*)take((size_t)N_EDGES * 8);
    unsigned int*       hist    = (unsigned int*)take((size_t)16 * 256 * 4); // per-pass bins
    SelState*           stArr   = (SelState*)take((size_t)16 * sizeof(SelState));
    unsigned long long* kthbuf  = (unsigned long long*)take(256);
    int*                bsum    = (int*)take((size_t)SCAN_NB * 4);
    int*                cnt_a   = (int*)take((size_t)HC_NB * 4);
    int*                cnt_b   = (int*)take((size_t)HC_NB * 4);

    // candidate slice buffers alias dead memory during the radix passes:
    // nh is dead after coskey (aggregate now reads raw h + nrm, NOT nh);
    // hB is never written (hop-2 aggregate writes `out` directly via fused fc).
    unsigned long long* candA = (unsigned long long*)nh;
    unsigned long long* candB = (unsigned long long*)hB;

    hipMemsetAsync(deg, 0, (size_t)N_NODES * 4, stream);
    hipMemsetAsync(hist, 0, (size_t)16 * 256 * 4, stream);

    deg_kernel<<<(N_EDGES + 255) / 256, 256, 0, stream>>>(dst, deg, rank, N_EDGES);
    blocksum_kernel<<<SCAN_NB, 256, 0, stream>>>(deg, bsum, nrm, N_NODES);
    writeoffs_kernel<<<SCAN_NB, 256, 0, stream>>>(deg, bsum, offs, N_NODES);
    fill_kernel<<<(N_EDGES + 255) / 256, 256, 0, stream>>>(src, dst, rank, offs, csr, N_EDGES);

    const float* hin = features;
    for (int hop = 0; hop < 2; ++hop) {
        unsigned int* hh = hist + (size_t)hop * 8 * 256;   // per-pass histograms
        SelState*     hst = stArr + (size_t)hop * 8;       // slots [1..2] used
        rownorm_kernel<<<(N_NODES + 255) / 256, 256, 0, stream>>>(hin, nh, N_NODES);
        coskey_kernel<<<COSKEY_NB, 256, 0, stream>>>(nh, csr, keys, hh, N_EDGES);
        // pass 1: dense keys -> candA slices
        histc_kernel<<<HC_NB, 256, 0, stream>>>(keys, nullptr, candA, cnt_a,
                                                nullptr, hst + 1,
                                                hh + 0 * 256, hh + 1 * 256, 1);
        // pass 2: candA slices -> candB slices
        histc_kernel<<<HC_NB, 256, 0, stream>>>(candA, cnt_a, candB, cnt_b,
                                                hst + 1, hst + 2,
                                                hh + 1 * 256, hh + 2 * 256, 2);
        // passes 3..7 + final select in ONE single-block launch
        tail_kernel<<<1, 256, 0, stream>>>(candB, cnt_b, candA,
                                           hst + 2, hh + 2 * 256, kthbuf + hop);
        if (hop == 0) {
            aggregate_csr_kernel<false><<<(N_NODES + 7) / 8, 256, 0, stream>>>(
                hin, hA, offs, csr, keys, kthbuf + hop, nrm, nullptr, N_NODES);
            hin = hA;
        } else {
            aggregate_csr_kernel<true><<<(N_NODES + 7) / 8, 256, 0, stream>>>(
                hin, out, offs, csr, keys, kthbuf + hop, nrm, W, N_NODES);
        }
    }
}